// Round 4
// baseline (337.367 us; speedup 1.0000x reference)
//
#include <hip/hip_runtime.h>
#include <stdint.h>

// MultiHeadAttention  B=8, S=2048, D=768  (fp32 in/out; bf16 MFMA compute)
//
// Pipeline:
//   convert : all 9 fp32 inputs -> bf16 in ws
//   qkv_k   : fused Q/K/V projections (grid 128x12, tile 128x192); Vt[b][e][s]
//   score_k : E = exp(min(Q.K^T/sqrt(D),30)) bf16 + fused rowsum -> rl (tile 128x256)
//   pv_k    : attn = (E @ V) * rcp(rl)   (grid 512, tile 128x192)
//   out_k   : out = attn@Wp^T + bp fp32  (grid 512, tile 128x192)
//
// *** This round: 2 blocks/CU TLP + 2-phase core ***
// R0-R3 evidence: MfmaUtil 24-30% with NOTHING saturated (VALU 15%, LDS ~26%,
// HBM <25%) = barrier-lockstep latency. At 1 block/CU all 8 waves converge at
// every phase barrier; ds_read->lgkm->MFMA serialize with no overlap. R0's
// un-pipelined core at ~2.6 blocks/CU matched the pipelined 256^2 at 1/CU ->
// TLP is what hides the lockstep. New core: tile 128x192 (NQ=3) / BK=64 /
// 8 waves (2Mx4N, wave C = 64x48) / LDS dbuf 80 KB -> 2 blocks/CU,
// __launch_bounds__(512,4). 2 phases per K-tile (16+8 MFMA), counted vmcnt,
// inline-asm ds_read + rule-18 fences. score_k: 128x256 NQ=4 (1/CU, 4.0 exact
// rounds). Grids all integer rounds at their occupancy.

typedef __attribute__((ext_vector_type(8))) short short8;
typedef __attribute__((ext_vector_type(4))) float f32x4;

typedef const __attribute__((address_space(1))) void gvoid_t;
typedef __attribute__((address_space(3))) void lvoid_t;

__device__ __forceinline__ float b2f(unsigned short u) {
  union { unsigned int u; float f; } v;
  v.u = ((unsigned int)u) << 16;
  return v.f;
}
__device__ __forceinline__ unsigned short f2b(float f) {
  union { float f; unsigned int u; } v; v.f = f;
  unsigned int u = v.u;
  return (unsigned short)((u + 0x7fffu + ((u >> 16) & 1u)) >> 16);
}

// ---------------- fp32 -> bf16 conversion ----------------
struct Cvt9 {
  const void* s[9];
  unsigned short* d[9];
  long long n8[9];
  long long total8;
};

__global__ __launch_bounds__(256) void convert_inputs(Cvt9 C) {
  long long g = (long long)blockIdx.x * 256 + threadIdx.x;
  if (g >= C.total8) return;
  int s = 0;
  long long off = g;
  while (off >= C.n8[s]) { off -= C.n8[s]; ++s; }
  const float* sf = (const float*)C.s[s] + off * 8;
  unsigned short* dp = C.d[s] + off * 8;
  float4 a = ((const float4*)sf)[0];
  float4 b = ((const float4*)sf)[1];
  uint4 o;
  o.x = (unsigned int)f2b(a.x) | ((unsigned int)f2b(a.y) << 16);
  o.y = (unsigned int)f2b(a.z) | ((unsigned int)f2b(a.w) << 16);
  o.z = (unsigned int)f2b(b.x) | ((unsigned int)f2b(b.y) << 16);
  o.w = (unsigned int)f2b(b.z) | ((unsigned int)f2b(b.w) << 16);
  *(uint4*)dp = o;
}

// ---------------- 128x(64*NQ) 2-phase GEMM core ----------------
// C[m0..+128][n0..+64NQ] += A[m0..][0..K) . B[n0..][0..K)^T  (both NT-major, bf16)
// LDS buffer p at p*(2+NQ)*8192 B: A 128x64 (16 KB = 2 quarters), B (64NQ)x64.
// Quarter (64 rows) = 8192 B staging unit; 8-slot rotation swizzle
// (src slot = (t&7)^((t>>3)&7); read slot = kc-chunk ^ (row&7)) -> 2-way free.
// Per K-tile: ph1 {read all frags; MMA ni 0,1} ph2 {stage kt+2; VM(2+NQ); MMA rest}.
template<int NQ>
__device__ __forceinline__ void gemm128(
    const unsigned short* __restrict__ Ag,   // pre-offset to (m0, 0), lda shorts
    const unsigned short* __restrict__ Bg,   // pre-offset to (n0, 0), ldb shorts
    const int lda, const int ldb, const int NT,
    unsigned short* lds, f32x4 (&acc)[4][NQ])
{
  const int t    = threadIdx.x;
  const int w    = t >> 6;
  const int lane = t & 63;
  const int lo   = lane & 15;
  const int quad = lane >> 4;
  const int wr   = w >> 2;          // 0..1  (row half: 64 rows)
  const int wcn  = w & 3;           // 0..3  (col quarter: 16*NQ cols)
  const int swz  = ((t & 7) ^ ((t >> 3) & 7)) << 3;   // pre-swizzled src k-slot (shorts)
  const int wslot = w * 512;                          // wave slot in a stage quarter (shorts)
  constexpr int SBUF_B = (2 + NQ) * 8192;             // buffer stride bytes
  constexpr int SBUF_S = SBUF_B / 2;                  // shorts

  const unsigned lbase = (unsigned)(uintptr_t)(void*)lds;
  const unsigned sb0 = (unsigned)((quad ^ (lo & 7)) << 4);        // k-chunk 0 slot (bytes)
  const unsigned sb1 = (unsigned)(((4 + quad) ^ (lo & 7)) << 4);  // k-chunk 1 slot (bytes)
  const unsigned aA0 = lbase + (unsigned)(wr * 64 + lo) * 128 + sb0;
  const unsigned aA1 = lbase + (unsigned)(wr * 64 + lo) * 128 + sb1;
  const unsigned aB0 = lbase + 16384u + (unsigned)(wcn * 16 * NQ + lo) * 128 + sb0;
  const unsigned aB1 = lbase + 16384u + (unsigned)(wcn * 16 * NQ + lo) * 128 + sb1;

  short8 af[4][2], bf[NQ][2];

#define STG(gb, ld, kt, q, soff)                                                  \
  __builtin_amdgcn_global_load_lds(                                               \
      (gvoid_t*)((gb) + (size_t)((q) * 64 + (t >> 3)) * (ld) + (kt) * 64 + swz),  \
      (lvoid_t*)(lds + ((kt) & 1) * SBUF_S + (soff) + wslot), 16, 0, 0)
#define SALL(kt) { STG(Ag, lda, (kt), 0, 0); STG(Ag, lda, (kt), 1, 4096);      \
                   STG(Bg, ldb, (kt), 0, 8192); STG(Bg, ldb, (kt), 1, 12288);  \
                   STG(Bg, ldb, (kt), 2, 16384);                               \
                   if constexpr (NQ == 4) STG(Bg, ldb, (kt), 3, 20480); }
// inline-asm LDS read: invisible to memory legalizer (no auto vmcnt drain)
#define DSR(d, a, IMM) asm volatile("ds_read_b128 %0, %1 offset:" #IMM : "=v"(d) : "v"(a))
#define RDALL(bo) {                                                   \
  const unsigned a0_ = aA0 + (bo);                                    \
  const unsigned a1_ = aA1 + (bo);                                    \
  DSR(af[0][0], a0_, 0);    DSR(af[0][1], a1_, 0);                    \
  DSR(af[1][0], a0_, 2048); DSR(af[1][1], a1_, 2048);                 \
  DSR(af[2][0], a0_, 4096); DSR(af[2][1], a1_, 4096);                 \
  DSR(af[3][0], a0_, 6144); DSR(af[3][1], a1_, 6144);                 \
  const unsigned b0_ = aB0 + (bo);                                    \
  const unsigned b1_ = aB1 + (bo);                                    \
  DSR(bf[0][0], b0_, 0);    DSR(bf[0][1], b1_, 0);                    \
  DSR(bf[1][0], b0_, 2048); DSR(bf[1][1], b1_, 2048);                 \
  DSR(bf[2][0], b0_, 4096); DSR(bf[2][1], b1_, 4096);                 \
  if constexpr (NQ == 4) { DSR(bf[3][0], b0_, 6144); DSR(bf[3][1], b1_, 6144); } }
#define MMA(NLO, NHI) {                                                       \
  __builtin_amdgcn_s_barrier();                                               \
  asm volatile("s_waitcnt lgkmcnt(0)" ::: "memory");                          \
  __builtin_amdgcn_sched_barrier(0);                                          \
  __builtin_amdgcn_s_setprio(1);                                              \
  _Pragma("unroll") for (int kc = 0; kc < 2; ++kc)                            \
  _Pragma("unroll") for (int mi = 0; mi < 4; ++mi)                            \
  _Pragma("unroll") for (int ni = (NLO); ni < (NHI); ++ni)                    \
    acc[mi][ni] = __builtin_amdgcn_mfma_f32_16x16x32_bf16(                    \
        af[mi][kc], bf[ni][kc], acc[mi][ni], 0, 0, 0);                        \
  __builtin_amdgcn_s_setprio(0);                                              \
  __builtin_amdgcn_sched_barrier(0);                                          \
  __builtin_amdgcn_s_barrier(); }
#define VMN() { if constexpr (NQ == 3) asm volatile("s_waitcnt vmcnt(5)" ::: "memory"); \
                else                   asm volatile("s_waitcnt vmcnt(6)" ::: "memory"); }

  // prologue: tiles 0 and 1 staged; wait tile 0 (tile 1 stays in flight)
  SALL(0); SALL(1);
  VMN();
  __builtin_amdgcn_s_barrier();

  for (int kt = 0; kt < NT - 2; ++kt) {
    const unsigned bo = (unsigned)((kt & 1) * SBUF_B);
    // ph1: read ALL fragments of tile kt, compute ni 0..1
    RDALL(bo);
    MMA(0, 2);
    // ph2: stage tile kt+2 (reads of buf p retired at ph1's lgkm0+barrier);
    //      counted wait completes tile kt+1; compute remaining ni
    SALL(kt + 2);
    VMN();
    MMA(2, NQ);
  }
  { // kt = NT-2: no staging; drain tile NT-1
    const unsigned bo = (unsigned)((NT & 1) * SBUF_B);    // (NT-2)&1 == NT&1
    RDALL(bo);
    MMA(0, 2);
    asm volatile("s_waitcnt vmcnt(0)" ::: "memory");
    MMA(2, NQ);
  }
  { // kt = NT-1: all data resident
    const unsigned bo = (unsigned)(((NT - 1) & 1) * SBUF_B);
    RDALL(bo);
    MMA(0, 2);
    MMA(2, NQ);
  }
#undef STG
#undef SALL
#undef DSR
#undef RDALL
#undef MMA
#undef VMN
}

// ---------------- bf16 epilogue: full 128 x 64NQ tile through LDS ----------------
// MODE 0: v += bias ; MODE 2: v = exp(min(v*scale,30)) ; MODE 3: v *= rcp(rl[row])
template<int MODE, int NQ>
__device__ __forceinline__ void epi_bf16(
    unsigned short* Ls, f32x4 (&acc)[4][NQ],
    const unsigned short* bias_n0, const float* rlbase, float scale,
    unsigned short* Cg, int ldc)
{
  constexpr int RS = 64 * NQ + 8;   // LDS row stride (shorts), 16B-aligned
  const int t = threadIdx.x, w = t >> 6, lane = t & 63;
  const int lo = lane & 15, quad = lane >> 4, wr = w >> 2, wcn = w & 3;
  __syncthreads();
  {
    float bvv[NQ];
    if (MODE == 0) {
#pragma unroll
      for (int nf = 0; nf < NQ; ++nf) bvv[nf] = b2f(bias_n0[wcn * 16 * NQ + nf * 16 + lo]);
    }
#pragma unroll
    for (int mf = 0; mf < 4; ++mf) {
      const int r0 = wr * 64 + mf * 16 + quad * 4;
      float rv[4];
      if (MODE == 3) {
#pragma unroll
        for (int r = 0; r < 4; ++r) rv[r] = __builtin_amdgcn_rcpf(rlbase[r0 + r]);
      }
#pragma unroll
      for (int nf = 0; nf < NQ; ++nf) {
        const int col = wcn * 16 * NQ + nf * 16 + lo;
#pragma unroll
        for (int r = 0; r < 4; ++r) {
          float v = acc[mf][nf][r];
          if (MODE == 0)      v += bvv[nf];
          else if (MODE == 2) v = __expf(fminf(v * scale, 30.f));
          else if (MODE == 3) v *= rv[r];
          Ls[(r0 + r) * RS + col] = f2b(v);
        }
      }
    }
  }
  __syncthreads();
#pragma unroll
  for (int u0 = 0; u0 < 2 * NQ; ++u0) {
    const int u = u0 * 512 + t, row = u / (8 * NQ), c16 = (u % (8 * NQ)) * 8;
    *(uint4*)(Cg + (size_t)row * ldc + c16) = *(const uint4*)(Ls + row * RS + c16);
  }
}

// ---------------- qkv: fused projections (tile 128x192) ----------------
__global__ __launch_bounds__(512, 4) void qkv_k(
    const unsigned short* __restrict__ xb,
    const unsigned short* __restrict__ Wq, const unsigned short* __restrict__ bq,
    const unsigned short* __restrict__ Wk, const unsigned short* __restrict__ bk,
    const unsigned short* __restrict__ Wv, const unsigned short* __restrict__ bv,
    unsigned short* __restrict__ qb, unsigned short* __restrict__ kb,
    unsigned short* __restrict__ vt)
{
  __shared__ unsigned short smem[40960];   // 81920 B = 2 x (2+3)*8192
  const int sel = blockIdx.y >> 2;
  const int n0  = (blockIdx.y & 3) * 192;
  const int m0  = blockIdx.x * 128;

  const unsigned short* W;
  const unsigned short* bi;
  if (sel == 0)      { W = Wq; bi = bq; }
  else if (sel == 1) { W = Wk; bi = bk; }
  else               { W = Wv; bi = bv; }

  f32x4 acc[4][3] = {};
  gemm128<3>(xb + (size_t)m0 * 768, W + (size_t)n0 * 768, 768, 768, 12, smem, acc);

  if (sel < 2) {
    unsigned short* dst = (sel == 0 ? qb : kb) + (size_t)m0 * 768 + n0;
    epi_bf16<0, 3>(smem, acc, bi + n0, nullptr, 0.f, dst, 768);
    return;
  }

  // V: transposed epilogue into Vt[b][e][s]; 3 e-chunks of 64, Ls [64][136]
  const int t = threadIdx.x, w = t >> 6, lane = t & 63;
  const int lo = lane & 15, quad = lane >> 4, wr = w >> 2, wcn = w & 3;
  const int bb2 = m0 >> 11, sin = m0 & 2047;
  unsigned short* Ls = smem;
#pragma unroll
  for (int ec = 0; ec < 3; ++ec) {
    __syncthreads();
#pragma unroll
    for (int nf = 0; nf < 3; ++nf) {
      const int ebase = wcn * 48 + nf * 16;
      if ((ebase >> 6) == ec) {
        const float bvv = b2f(bi[n0 + ebase + lo]);
#pragma unroll
        for (int mf = 0; mf < 4; ++mf) {
          const int srow = wr * 64 + mf * 16 + quad * 4;
          ushort4 pk;
          pk.x = f2b(acc[mf][nf][0] + bvv);
          pk.y = f2b(acc[mf][nf][1] + bvv);
          pk.z = f2b(acc[mf][nf][2] + bvv);
          pk.w = f2b(acc[mf][nf][3] + bvv);
          *(ushort4*)(Ls + ((ebase & 63) + lo) * 136 + srow) = pk;
        }
      }
    }
    __syncthreads();
    unsigned short* Vb = vt + (size_t)bb2 * 1572864 + (size_t)(n0 + ec * 64) * 2048 + sin;
#pragma unroll
    for (int u0 = 0; u0 < 2; ++u0) {
      const int u = u0 * 512 + t, e = u >> 4, s16 = (u & 15) * 8;
      *(uint4*)(Vb + (size_t)e * 2048 + s16) = *(const uint4*)(Ls + e * 136 + s16);
    }
  }
}

// ---------------- score: E = exp(QK^T/sqrt(D)) + fused rowsum (tile 128x256) ----------------
__global__ __launch_bounds__(512, 2) void score_k(
    const unsigned short* __restrict__ Q, const unsigned short* __restrict__ Kb,
    unsigned short* __restrict__ E, float* __restrict__ rl, float scale)
{
  __shared__ unsigned short smem[49152];   // 98304 B = 2 x (2+4)*8192
  const int m0 = blockIdx.x * 128, n0 = blockIdx.y * 256, bz = blockIdx.z;

  f32x4 acc[4][4] = {};
  gemm128<4>(Q + (size_t)bz * 1572864 + (size_t)m0 * 768,
             Kb + (size_t)bz * 1572864 + (size_t)n0 * 768, 768, 768, 12, smem, acc);

  unsigned short* Eg = E + (size_t)bz * 4194304 + (size_t)m0 * 2048 + n0;
  epi_bf16<2, 4>(smem, acc, nullptr, nullptr, scale, Eg, 2048);

  // fused partial rowsum from staged LDS tile (4 threads/row, rotated reads)
  const int t = threadIdx.x;
  const int row = t >> 2, seg = t & 3;
  const unsigned short* lr = smem + row * 264 + seg * 64;
  float s = 0.f;
#pragma unroll
  for (int q8 = 0; q8 < 8; ++q8) {
    const int qq = ((q8 + row) & 7) * 8;
    uint4 v = *(const uint4*)(lr + qq);
    unsigned int uu[4] = {v.x, v.y, v.z, v.w};
#pragma unroll
    for (int c = 0; c < 4; ++c)
      s += b2f((unsigned short)(uu[c] & 0xffffu)) + b2f((unsigned short)(uu[c] >> 16));
  }
  s += __shfl_xor(s, 1);
  s += __shfl_xor(s, 2);
  if (seg == 0) atomicAdd(rl + bz * 2048 + m0 + row, s);
}

// ---------------- pv: attn = (E @ V) * rcp(rowsum) (tile 128x192) ----------------
__global__ __launch_bounds__(512, 4) void pv_k(
    const unsigned short* __restrict__ E, const unsigned short* __restrict__ Vt,
    const float* __restrict__ rl, unsigned short* __restrict__ attn)
{
  __shared__ unsigned short smem[40960];
  const int m0 = blockIdx.x * 128, n0 = blockIdx.y * 192, bz = blockIdx.z;

  f32x4 acc[4][3] = {};
  gemm128<3>(E + (size_t)bz * 4194304 + (size_t)m0 * 2048,
             Vt + (size_t)bz * 1572864 + (size_t)n0 * 2048, 2048, 2048, 32, smem, acc);

  const float* rlb = rl + bz * 2048 + m0;
  unsigned short* Cg = attn + (size_t)bz * 1572864 + (size_t)m0 * 768 + n0;
  epi_bf16<3, 3>(smem, acc, nullptr, rlb, 0.f, Cg, 768);
}

// ---------------- out: final projection (fp32 output, tile 128x192) ----------------
__global__ __launch_bounds__(512, 4) void out_k(
    const unsigned short* __restrict__ attn,
    const unsigned short* __restrict__ Wp, const unsigned short* __restrict__ bp,
    float* __restrict__ Of)
{
  __shared__ unsigned short smem[40960];
  const int m0 = blockIdx.x * 128, n0 = blockIdx.y * 192;

  f32x4 acc[4][3] = {};
  gemm128<3>(attn + (size_t)m0 * 768, Wp + (size_t)n0 * 768, 768, 768, 12, smem, acc);

  // fp32 output: 2 passes of 64 rows staged as float through LDS [64][200]
  const int t = threadIdx.x, w = t >> 6, lane = t & 63;
  const int lo = lane & 15, quad = lane >> 4, wr = w >> 2, wcn = w & 3;
  float* Lf = (float*)smem;
#pragma unroll
  for (int p = 0; p < 2; ++p) {
    __syncthreads();
    if (wr == p) {
#pragma unroll
      for (int mf = 0; mf < 4; ++mf) {
        const int r0 = mf * 16 + quad * 4;
#pragma unroll
        for (int nf = 0; nf < 3; ++nf) {
          const int col = wcn * 48 + nf * 16 + lo;
          const float bvv = b2f(bp[n0 + col]);
#pragma unroll
          for (int r = 0; r < 4; ++r)
            Lf[(r0 + r) * 200 + col] = acc[mf][nf][r] + bvv;
        }
      }
    }
    __syncthreads();
#pragma unroll
    for (int u0 = 0; u0 < 6; ++u0) {
      const int u = u0 * 512 + t, row = u / 48, c4 = (u % 48) * 4;
      *(float4*)(Of + (size_t)(m0 + p * 64 + row) * 768 + n0 + c4) =
          *(const float4*)(Lf + row * 200 + c4);
    }
  }
}

extern "C" void kernel_launch(void* const* d_in, const int* in_sizes, int n_in,
                              void* d_out, int out_size, void* d_ws, size_t ws_size,
                              hipStream_t stream) {
  (void)in_sizes; (void)n_in; (void)out_size; (void)ws_size;

  char* ws = (char*)d_ws;
  float* rl    = (float*)(ws + 4096);
  unsigned short* wcv = (unsigned short*)(ws + ((size_t)1 << 20));
  unsigned short* qb  = (unsigned short*)(ws + ((size_t)8  << 20));
  unsigned short* kb  = (unsigned short*)(ws + ((size_t)32 << 20));
  unsigned short* vt  = (unsigned short*)(ws + ((size_t)56 << 20));
  unsigned short* eb  = (unsigned short*)(ws + ((size_t)80 << 20));
  unsigned short* xb  = eb;     // converted x aliases E (x dead before score_k writes E)
  unsigned short* attn = qb;    // Q dead after score_k

  unsigned short* wqb = wcv;
  unsigned short* bqb = wcv + 589824;
  unsigned short* wkb = wcv + 590592;
  unsigned short* bkb = wcv + 1180416;
  unsigned short* wvb = wcv + 1181184;
  unsigned short* bvb = wcv + 1771008;
  unsigned short* wpb = wcv + 1771776;
  unsigned short* bpb = wcv + 2361600;

  const float inv_scale = 0.036084391824351615f;  // 1/sqrt(768)

  Cvt9 cv;
  cv.s[0] = d_in[0]; cv.d[0] = xb;  cv.n8[0] = 12582912 / 8;
  cv.s[1] = d_in[1]; cv.d[1] = wqb; cv.n8[1] = 589824 / 8;
  cv.s[2] = d_in[2]; cv.d[2] = bqb; cv.n8[2] = 768 / 8;
  cv.s[3] = d_in[3]; cv.d[3] = wkb; cv.n8[3] = 589824 / 8;
  cv.s[4] = d_in[4]; cv.d[4] = bkb; cv.n8[4] = 768 / 8;
  cv.s[5] = d_in[5]; cv.d[5] = wvb; cv.n8[5] = 589824 / 8;
  cv.s[6] = d_in[6]; cv.d[6] = bvb; cv.n8[6] = 768 / 8;
  cv.s[7] = d_in[7]; cv.d[7] = wpb; cv.n8[7] = 589824 / 8;
  cv.s[8] = d_in[8]; cv.d[8] = bpb; cv.n8[8] = 768 / 8;
  cv.total8 = (12582912 + 4 * (589824 + 768)) / 8;
  convert_inputs<<<(unsigned)((cv.total8 + 255) / 256), dim3(256), 0, stream>>>(cv);

  hipMemsetAsync(rl, 0, 16384 * sizeof(float), stream);

  qkv_k<<<dim3(128, 12, 1), dim3(512), 0, stream>>>(xb, wqb, bqb, wkb, bkb, wvb, bvb, qb, kb, vt);

  score_k<<<dim3(16, 8, 8), dim3(512), 0, stream>>>(qb, kb, eb, rl, inv_scale);

  pv_k<<<dim3(16, 4, 8), dim3(512), 0, stream>>>(eb, vt, rl, attn);

  out_k<<<dim3(128, 4, 1), dim3(512), 0, stream>>>(attn, wpb, bpb, (float*)d_out);
}